// Round 1
// baseline (152.478 us; speedup 1.0000x reference)
//
#include <hip/hip_runtime.h>
#include <math.h>

#define NN 4096
#define F_IN 512
#define HEADS 8
#define D_HEAD 8
#define C1 64
#define NCLASS 16
#define MAX_DEG 128
#define LEAKY 0.2f

// ---------------- Kernel A: h1 = x @ W1 (per head), fused e_src/e_dst ----------------
// grid 256 blocks x 256 thr; block handles 16 rows; thread t: c=t&63 (h*8+d), rr=t>>6 -> rows rr*4..rr*4+3
__global__ __launch_bounds__(256) void k_proj1(const float* __restrict__ x,
                                               const float* __restrict__ W1,
                                               const float* __restrict__ a1s,
                                               const float* __restrict__ a1d,
                                               float* __restrict__ h1,
                                               float* __restrict__ es1,
                                               float* __restrict__ ed1) {
    __shared__ float xs[16 * 512];
    const int t = threadIdx.x;
    const int n0 = blockIdx.x * 16;
    // stage 16 rows of x (32 KB) into LDS, float4 coalesced
    const float4* x4 = (const float4*)(x + (size_t)n0 * F_IN);
    float4* xs4 = (float4*)xs;
#pragma unroll
    for (int i = 0; i < 8; i++) xs4[t + i * 256] = x4[t + i * 256];
    __syncthreads();

    const int c = t & 63;
    const int h = c >> 3, d = c & 7;
    const int rr = t >> 6;
    const float* wp = W1 + h * (F_IN * D_HEAD) + d;
    const float* xr0 = xs + (rr * 4 + 0) * F_IN;
    const float* xr1 = xs + (rr * 4 + 1) * F_IN;
    const float* xr2 = xs + (rr * 4 + 2) * F_IN;
    const float* xr3 = xs + (rr * 4 + 3) * F_IN;
    float a0 = 0.f, a1 = 0.f, a2 = 0.f, a3 = 0.f;
#pragma unroll 8
    for (int f = 0; f < F_IN; f++) {
        float w = wp[f * 8];
        a0 += xr0[f] * w;
        a1 += xr1[f] * w;
        a2 += xr2[f] * w;
        a3 += xr3[f] * w;
    }
    const float as = a1s[c], ad = a1d[c];
    float accs[4] = {a0, a1, a2, a3};
#pragma unroll
    for (int q = 0; q < 4; q++) {
        int n = n0 + rr * 4 + q;
        float v = accs[q];
        h1[(size_t)n * C1 + c] = v;
        float vs = v * as, vd = v * ad;
        vs += __shfl_xor(vs, 1, 64); vd += __shfl_xor(vd, 1, 64);
        vs += __shfl_xor(vs, 2, 64); vd += __shfl_xor(vd, 2, 64);
        vs += __shfl_xor(vs, 4, 64); vd += __shfl_xor(vd, 4, 64);
        if (d == 0) { es1[n * HEADS + h] = vs; ed1[n * HEADS + h] = vd; }
    }
}

// ---------------- Kernel B: build CSR from dense adj (read adj exactly once) ----------------
__global__ __launch_bounds__(256) void k_csr(const float* __restrict__ adj,
                                             int* __restrict__ deg,
                                             int* __restrict__ cols) {
    __shared__ int cnt;
    __shared__ int cls[MAX_DEG];
    const int n = blockIdx.x, t = threadIdx.x;
    if (t == 0) cnt = 0;
    __syncthreads();
    const float4* row4 = (const float4*)(adj + (size_t)n * NN);
#pragma unroll
    for (int i = 0; i < 4; i++) {
        float4 v = row4[i * 256 + t];
        int base = (i * 256 + t) * 4;
        if (v.x > 0.f) { int p = atomicAdd(&cnt, 1); if (p < MAX_DEG) cls[p] = base; }
        if (v.y > 0.f) { int p = atomicAdd(&cnt, 1); if (p < MAX_DEG) cls[p] = base + 1; }
        if (v.z > 0.f) { int p = atomicAdd(&cnt, 1); if (p < MAX_DEG) cls[p] = base + 2; }
        if (v.w > 0.f) { int p = atomicAdd(&cnt, 1); if (p < MAX_DEG) cls[p] = base + 3; }
    }
    __syncthreads();
    int dc = cnt < MAX_DEG ? cnt : MAX_DEG;
    if (t == 0) deg[n] = dc;
    for (int i = t; i < dc; i += 256) cols[n * MAX_DEG + i] = cls[i];
}

// ---------------- Kernel C: layer-1 attention+aggregate, ELU, W2 proj, e2 dots ----------------
// 1 wave per node; thread t = channel c = h*8+d
__global__ __launch_bounds__(64) void k_layer1(const float* __restrict__ h1,
                                               const float* __restrict__ es1,
                                               const float* __restrict__ ed1,
                                               const int* __restrict__ deg,
                                               const int* __restrict__ cols,
                                               const float* __restrict__ W2,
                                               const float* __restrict__ a2s,
                                               const float* __restrict__ a2d,
                                               float* __restrict__ h2,
                                               float* __restrict__ es2,
                                               float* __restrict__ ed2) {
    __shared__ int cls[MAX_DEG];
    __shared__ float row[C1];
    const int n = blockIdx.x, t = threadIdx.x;
    const int dg = deg[n];
    for (int i = t; i < dg; i += 64) cls[i] = cols[n * MAX_DEG + i];
    __syncthreads();
    const int h = t >> 3;
    const float es = es1[n * HEADS + h];
    float M = -1e30f, S = 0.f, acc = 0.f;
    // 1-deep software pipeline on the neighbor gather
    int m = cls[0];
    float edv = ed1[m * HEADS + h];
    float hv = h1[(size_t)m * C1 + t];
    for (int j = 0; j < dg; j++) {
        float edc = edv, hvc = hv;
        if (j + 1 < dg) {
            int m2 = cls[j + 1];
            edv = ed1[m2 * HEADS + h];
            hv = h1[(size_t)m2 * C1 + t];
        }
        float e = es + edc;
        e = e > 0.f ? e : LEAKY * e;
        float Mn = fmaxf(M, e);
        float sc = __expf(M - Mn);
        float p = __expf(e - Mn);
        acc = acc * sc + p * hvc;
        S = S * sc + p;
        M = Mn;
    }
    float o = acc / S;
    o = o > 0.f ? o : __expf(o) - 1.f;  // ELU
    row[t] = o;
    __syncthreads();
    // h2[k] = sum_c row[c]*W2[c*16+k]; 4 groups of 16 c's, then shfl-combine
    const int k = t & 15, g = t >> 4;
    float hk = 0.f;
#pragma unroll
    for (int cc = 0; cc < 16; cc++) {
        int c = g * 16 + cc;
        hk += row[c] * W2[c * NCLASS + k];
    }
    hk += __shfl_xor(hk, 16, 64);
    hk += __shfl_xor(hk, 32, 64);
    if (t < 16) h2[n * NCLASS + k] = hk;
    float vs = hk * a2s[k];
    float vd = hk * a2d[k];
#pragma unroll
    for (int msk = 8; msk >= 1; msk >>= 1) {
        vs += __shfl_xor(vs, msk, 64);
        vd += __shfl_xor(vd, msk, 64);
    }
    if (t == 0) { es2[n] = vs; ed2[n] = vd; }
}

// ---------------- Kernel D: layer-2 attention+aggregate + log_softmax ----------------
// 1 wave per node; lane t: k=t&15, neighbor-group g=t>>4 (4 groups)
__global__ __launch_bounds__(64) void k_layer2(const float* __restrict__ h2,
                                               const float* __restrict__ es2,
                                               const float* __restrict__ ed2,
                                               const int* __restrict__ deg,
                                               const int* __restrict__ cols,
                                               float* __restrict__ out) {
    __shared__ int cls[MAX_DEG];
    const int n = blockIdx.x, t = threadIdx.x;
    const int dg = deg[n];
    for (int i = t; i < dg; i += 64) cls[i] = cols[n * MAX_DEG + i];
    __syncthreads();
    const int k = t & 15, g = t >> 4;
    const float es = es2[n];
    float M = -1e30f, S = 0.f, acc = 0.f;
    for (int j = g; j < dg; j += 4) {
        int m = cls[j];
        float e = es + ed2[m];
        e = e > 0.f ? e : LEAKY * e;
        float hv = h2[m * NCLASS + k];
        float Mn = fmaxf(M, e);
        float sc = __expf(M - Mn);
        float p = __expf(e - Mn);
        acc = acc * sc + p * hv;
        S = S * sc + p;
        M = Mn;
    }
    // flash-combine the 4 groups across lanes (xor 16, 32)
#pragma unroll
    for (int msk = 16; msk <= 32; msk <<= 1) {
        float Mo = __shfl_xor(M, msk, 64);
        float So = __shfl_xor(S, msk, 64);
        float ao = __shfl_xor(acc, msk, 64);
        float Mn = fmaxf(M, Mo);
        float s1 = __expf(M - Mn), s2 = __expf(Mo - Mn);
        acc = acc * s1 + ao * s2;
        S = S * s1 + So * s2;
        M = Mn;
    }
    float v = acc / S;
    // log_softmax over the 16 classes (lanes k within each 16-lane group)
    float mx = v;
#pragma unroll
    for (int msk = 1; msk <= 8; msk <<= 1) mx = fmaxf(mx, __shfl_xor(mx, msk, 64));
    float ex = __expf(v - mx);
    float se = ex;
#pragma unroll
    for (int msk = 1; msk <= 8; msk <<= 1) se += __shfl_xor(se, msk, 64);
    float r = v - mx - __logf(se);
    if (t < 16) out[n * NCLASS + k] = r;
}

extern "C" void kernel_launch(void* const* d_in, const int* in_sizes, int n_in,
                              void* d_out, int out_size, void* d_ws, size_t ws_size,
                              hipStream_t stream) {
    const float* x   = (const float*)d_in[0];
    const float* adj = (const float*)d_in[1];
    const float* W1  = (const float*)d_in[2];
    const float* a1s = (const float*)d_in[3];
    const float* a1d = (const float*)d_in[4];
    const float* W2  = (const float*)d_in[5];
    const float* a2s = (const float*)d_in[6];
    const float* a2d = (const float*)d_in[7];
    float* out = (float*)d_out;

    float* ws  = (float*)d_ws;
    float* h1  = ws;                  // 4096*64
    float* es1 = h1 + NN * C1;        // 4096*8
    float* ed1 = es1 + NN * HEADS;    // 4096*8
    float* h2  = ed1 + NN * HEADS;    // 4096*16
    float* es2 = h2 + NN * NCLASS;    // 4096
    float* ed2 = es2 + NN;            // 4096
    int* deg  = (int*)(ed2 + NN);     // 4096
    int* cols = deg + NN;             // 4096*MAX_DEG

    k_proj1<<<NN / 16, 256, 0, stream>>>(x, W1, a1s, a1d, h1, es1, ed1);
    k_csr<<<NN, 256, 0, stream>>>(adj, deg, cols);
    k_layer1<<<NN, 64, 0, stream>>>(h1, es1, ed1, deg, cols, W2, a2s, a2d, h2, es2, ed2);
    k_layer2<<<NN, 64, 0, stream>>>(h2, es2, ed2, deg, cols, out);
}